// Round 1
// baseline (433.202 us; speedup 1.0000x reference)
//
#include <hip/hip_runtime.h>

#define GN 16384
#define GD 128
#define GH 512
#define GK 16384

typedef __attribute__((ext_vector_type(8))) short s8v;   // 8 x bf16 (as short)
typedef __attribute__((ext_vector_type(4))) float f4v;
typedef __attribute__((ext_vector_type(4))) int   i4v;

static __device__ inline unsigned short f2bf(float f) {
  union { float f; unsigned u; } a; a.f = f;
  unsigned r = a.u + 0x7fffu + ((a.u >> 16) & 1u);   // RNE
  return (unsigned short)(r >> 16);
}

static __device__ inline float waveAllSum(float v) {
  #pragma unroll
  for (int off = 32; off; off >>= 1) v += __shfl_xor(v, off);
  return v;
}

// ---------------- kernel 1: L = log_map_zero(exp_map_zero(x)) ----------------
// one wave per row; lane handles elements 2*lane, 2*lane+1
__global__ void k_logmap(const float* __restrict__ x, float* __restrict__ Lf) {
  int row  = (blockIdx.x << 2) + (threadIdx.x >> 6);
  int lane = threadIdx.x & 63;
  size_t base = ((size_t)row << 7) + (lane << 1);
  float2 v = *(const float2*)(x + base);
  float a0 = (lane == 0) ? 0.f : v.x;   // u[...,0] is ignored by exp_map
  float a1 = v.y;
  float n = fmaxf(sqrtf(waveAllSum(a0*a0 + a1*a1)), 1e-7f);
  float sh = sinhf(n), ch = coshf(n);
  float y0 = sh * a0 / n, y1 = sh * a1 / n;        // h[...,1:]
  float ny = fmaxf(sqrtf(waveAllSum(y0*y0 + y1*y1)), 1e-7f);
  float z  = fmaxf(ch, 1.f + 1e-7f);
  float th = logf(z + sqrtf(z*z - 1.f));           // arcosh(h0)
  float l0 = th * y0 / ny;
  float l1 = th * y1 / ny;
  if (lane == 0) l0 = 0.f;                         // L[...,0] = 0
  *(float2*)(Lf + base) = make_float2(l0, l1);
}

// ---------------- kernel 2: Lt[d][k] = bf16(L[k][d]) ----------------
__global__ void k_transpose(const float* __restrict__ Lf, unsigned short* __restrict__ Lt) {
  __shared__ float tile[64][65];
  const int k0 = blockIdx.x << 6;
  const int d0 = blockIdx.y << 6;
  const int t  = threadIdx.x;
  const int r  = t >> 2;
  const int cg = (t & 3) << 4;
  const float* src = Lf + (size_t)(k0 + r) * GD + d0 + cg;
  #pragma unroll
  for (int j = 0; j < 4; ++j) {
    float4 f = ((const float4*)src)[j];
    tile[r][cg + 4*j + 0] = f.x;
    tile[r][cg + 4*j + 1] = f.y;
    tile[r][cg + 4*j + 2] = f.z;
    tile[r][cg + 4*j + 3] = f.w;
  }
  __syncthreads();
  s8v o0, o1;
  #pragma unroll
  for (int j = 0; j < 8; ++j) o0[j] = (short)f2bf(tile[cg + j][r]);
  #pragma unroll
  for (int j = 0; j < 8; ++j) o1[j] = (short)f2bf(tile[cg + 8 + j][r]);
  unsigned short* dst = Lt + (size_t)(d0 + r) * GK + k0 + cg;
  *(s8v*)dst = o0;
  *((s8v*)dst + 1) = o1;
}

// ---------------- kernel 3: M = adj @ L  (bf16 MFMA, f32 accumulate) --------
// BM=64, BN=128, BK=128; 512 threads = 8 waves in 2x4 grid; 32x32 per wave.
#define PADK 136   // 128 + 8 shorts padding -> 272B rows, conflict-free-ish
__global__ __launch_bounds__(512) void k_gemm(const float* __restrict__ adj,
    const unsigned short* __restrict__ Lt, float* __restrict__ Mout) {
  __shared__ __align__(16) short As[64 * PADK];
  __shared__ __align__(16) short Bs[128 * PADK];
  const int tid  = threadIdx.x;
  const int lane = tid & 63, wid = tid >> 6;
  const int wr = wid >> 2, wc = wid & 3;
  const size_t blockRow = (size_t)blockIdx.x * 64;

  f4v acc[2][2];
  #pragma unroll
  for (int i = 0; i < 2; ++i)
    #pragma unroll
    for (int j = 0; j < 2; ++j) acc[i][j] = (f4v){0.f, 0.f, 0.f, 0.f};

  // staging maps
  const int arow = tid >> 3, acol = (tid & 7) << 4;        // 64 rows x 128 k (f32)
  const float* ap = adj + (blockRow + arow) * (size_t)GK + acol;
  const int brow = tid >> 2, bkg = (tid & 3) << 5;         // 128 d-rows x 128 k (bf16)
  const unsigned short* bp = Lt + (size_t)brow * GK + bkg;

  const int aoff = arow * PADK + acol;
  const int boff = brow * PADK + bkg;
  const int afrag = (32*wr + (lane & 15)) * PADK + ((lane >> 4) << 3);
  const int bfrag = (32*wc + (lane & 15)) * PADK + ((lane >> 4) << 3);

  float4 ra[4];
  i4v    rb[4];
  #pragma unroll
  for (int j = 0; j < 4; ++j) ra[j] = ((const float4*)ap)[j];
  #pragma unroll
  for (int j = 0; j < 4; ++j) rb[j] = ((const i4v*)bp)[j];

  const int NIT = GK / 128;
  for (int it = 0; it < NIT; ++it) {
    // write staged tile to LDS (convert adj f32 -> bf16)
    s8v s0, s1;
    s0[0]=(short)f2bf(ra[0].x); s0[1]=(short)f2bf(ra[0].y); s0[2]=(short)f2bf(ra[0].z); s0[3]=(short)f2bf(ra[0].w);
    s0[4]=(short)f2bf(ra[1].x); s0[5]=(short)f2bf(ra[1].y); s0[6]=(short)f2bf(ra[1].z); s0[7]=(short)f2bf(ra[1].w);
    s1[0]=(short)f2bf(ra[2].x); s1[1]=(short)f2bf(ra[2].y); s1[2]=(short)f2bf(ra[2].z); s1[3]=(short)f2bf(ra[2].w);
    s1[4]=(short)f2bf(ra[3].x); s1[5]=(short)f2bf(ra[3].y); s1[6]=(short)f2bf(ra[3].z); s1[7]=(short)f2bf(ra[3].w);
    *(s8v*)&As[aoff]     = s0;
    *(s8v*)&As[aoff + 8] = s1;
    #pragma unroll
    for (int j = 0; j < 4; ++j) *(i4v*)&Bs[boff + 8*j] = rb[j];
    __syncthreads();

    if (it + 1 < NIT) {           // prefetch next tile into registers
      const float* ap2 = ap + (size_t)(it + 1) * 128;
      const unsigned short* bp2 = bp + (size_t)(it + 1) * 128;
      #pragma unroll
      for (int j = 0; j < 4; ++j) ra[j] = ((const float4*)ap2)[j];
      #pragma unroll
      for (int j = 0; j < 4; ++j) rb[j] = ((const i4v*)bp2)[j];
    }

    #pragma unroll
    for (int kk = 0; kk < 128; kk += 32) {
      s8v a0 = *(const s8v*)&As[afrag + kk];
      s8v a1 = *(const s8v*)&As[afrag + 16*PADK + kk];
      s8v b0 = *(const s8v*)&Bs[bfrag + kk];
      s8v b1 = *(const s8v*)&Bs[bfrag + 16*PADK + kk];
      acc[0][0] = __builtin_amdgcn_mfma_f32_16x16x32_bf16(a0, b0, acc[0][0], 0, 0, 0);
      acc[0][1] = __builtin_amdgcn_mfma_f32_16x16x32_bf16(a0, b1, acc[0][1], 0, 0, 0);
      acc[1][0] = __builtin_amdgcn_mfma_f32_16x16x32_bf16(a1, b0, acc[1][0], 0, 0, 0);
      acc[1][1] = __builtin_amdgcn_mfma_f32_16x16x32_bf16(a1, b1, acc[1][1], 0, 0, 0);
    }
    __syncthreads();
  }

  // epilogue: C/D layout col = lane&15, row = (lane>>4)*4 + r
  #pragma unroll
  for (int mi = 0; mi < 2; ++mi)
    #pragma unroll
    for (int ni = 0; ni < 2; ++ni) {
      size_t r0 = blockRow + 32*wr + 16*mi + ((lane >> 4) << 2);
      int    c0 = 32*wc + 16*ni + (lane & 15);
      #pragma unroll
      for (int r2 = 0; r2 < 4; ++r2)
        Mout[(r0 + r2) * GD + c0] = acc[mi][ni][r2];
    }
}

// ---------------- kernel 4: out = exp(log(exp(M)) + L) ----------------------
__global__ void k_maps(const float* __restrict__ Mv, const float* __restrict__ Lf,
                       float* __restrict__ outM) {
  int row  = (blockIdx.x << 2) + (threadIdx.x >> 6);
  int lane = threadIdx.x & 63;
  size_t base = ((size_t)row << 7) + (lane << 1);
  float2 mv = *(const float2*)(Mv + base);
  float2 lv = *(const float2*)(Lf + base);
  float v0 = (lane == 0) ? 0.f : mv.x;
  float v1 = mv.y;
  float nv = fmaxf(sqrtf(waveAllSum(v0*v0 + v1*v1)), 1e-7f);
  float ch = coshf(nv), sh = sinhf(nv);
  float g0 = sh * v0 / nv, g1 = sh * v1 / nv;          // agg[...,1:]
  float ny = fmaxf(sqrtf(waveAllSum(g0*g0 + g1*g1)), 1e-7f);
  float z  = fmaxf(ch, 1.f + 1e-7f);
  float th = logf(z + sqrtf(z*z - 1.f));
  float la0 = th * g0 / ny, la1 = th * g1 / ny;        // log_map(agg)
  float s0 = la0 + lv.x, s1 = la1 + lv.y;              // + (1+eps)*L
  if (lane == 0) s0 = 0.f;                             // exp_map ignores s[...,0]
  float ns  = fmaxf(sqrtf(waveAllSum(s0*s0 + s1*s1)), 1e-7f);
  float ch2 = coshf(ns), sh2 = sinhf(ns);
  float o0 = sh2 * s0 / ns, o1 = sh2 * s1 / ns;
  if (lane == 0) o0 = ch2;                             // out[...,0] = cosh
  *(float2*)(outM + base) = make_float2(o0, o1);
}

// ---------------- kernel 5: T = relu(out@W1 + b1) @ W2 + b2 -----------------
// 16 rows per block, 256 threads (4 waves, 4 rows each)
__global__ __launch_bounds__(256) void k_mlp(const float* __restrict__ outM,
    const float* __restrict__ W1, const float* __restrict__ b1,
    const float* __restrict__ W2, const float* __restrict__ b2,
    float* __restrict__ Tout) {
  __shared__ float sH[16][GH];
  const int tid  = threadIdx.x;
  const int w    = tid >> 6, lane = tid & 63;
  const int row0 = blockIdx.x << 4;

  float acc[4][8];
  #pragma unroll
  for (int r = 0; r < 4; ++r)
    #pragma unroll
    for (int g = 0; g < 8; ++g) acc[r][g] = 0.f;

  const float* orow[4];
  #pragma unroll
  for (int r = 0; r < 4; ++r) orow[r] = outM + (size_t)(row0 + 4*w + r) * GD;

  for (int d = 0; d < GD; ++d) {
    float wv[8];
    #pragma unroll
    for (int g = 0; g < 8; ++g) wv[g] = W1[d * GH + (g << 6) + lane];
    #pragma unroll
    for (int r = 0; r < 4; ++r) {
      float o = orow[r][d];
      #pragma unroll
      for (int g = 0; g < 8; ++g) acc[r][g] = fmaf(o, wv[g], acc[r][g]);
    }
  }
  #pragma unroll
  for (int g = 0; g < 8; ++g) {
    float bb = b1[(g << 6) + lane];
    #pragma unroll
    for (int r = 0; r < 4; ++r)
      sH[4*w + r][(g << 6) + lane] = fmaxf(acc[r][g] + bb, 0.f);
  }
  __syncthreads();

  float acc2[4][2];
  #pragma unroll
  for (int r = 0; r < 4; ++r) { acc2[r][0] = 0.f; acc2[r][1] = 0.f; }
  for (int h = 0; h < GH; ++h) {
    float w2a = W2[h * GD + lane];
    float w2b = W2[h * GD + 64 + lane];
    #pragma unroll
    for (int r = 0; r < 4; ++r) {
      float hv = sH[4*w + r][h];
      acc2[r][0] = fmaf(hv, w2a, acc2[r][0]);
      acc2[r][1] = fmaf(hv, w2b, acc2[r][1]);
    }
  }
  float bb0 = b2[lane], bb1 = b2[64 + lane];
  #pragma unroll
  for (int r = 0; r < 4; ++r) {
    size_t o = (size_t)(row0 + 4*w + r) * GD;
    Tout[o + lane]      = acc2[r][0] + bb0;
    Tout[o + 64 + lane] = acc2[r][1] + bb1;
  }
}

extern "C" void kernel_launch(void* const* d_in, const int* in_sizes, int n_in,
                              void* d_out, int out_size, void* d_ws, size_t ws_size,
                              hipStream_t stream) {
  const float* x   = (const float*)d_in[0];
  const float* adj = (const float*)d_in[1];
  const float* W1  = (const float*)d_in[2];
  const float* b1  = (const float*)d_in[3];
  const float* W2  = (const float*)d_in[4];
  const float* b2  = (const float*)d_in[5];
  float* Tout = (float*)d_out;

  char* ws = (char*)d_ws;
  float*          Lf   = (float*)ws;                          // 8 MB
  unsigned short* Lt   = (unsigned short*)(ws + (8u  << 20)); // 4 MB
  float*          Mv   = (float*)(ws + (12u << 20));          // 8 MB
  float*          outM = (float*)(ws + (20u << 20));          // 8 MB  (total 28 MB)

  k_logmap   <<<GN / 4, 256, 0, stream>>>(x, Lf);
  k_transpose<<<dim3(GK / 64, GD / 64), 256, 0, stream>>>(Lf, Lt);
  k_gemm     <<<GN / 64, 512, 0, stream>>>(adj, Lt, Mv);
  k_maps     <<<GN / 4, 256, 0, stream>>>(Mv, Lf, outM);
  k_mlp      <<<GN / 16, 256, 0, stream>>>(outM, W1, b1, W2, b2, Tout);
}